// Round 2
// baseline (298.167 us; speedup 1.0000x reference)
//
#include <hip/hip_runtime.h>
#include <hip/hip_bf16.h>
#include <stdint.h>
#include <stddef.h>

typedef __attribute__((ext_vector_type(8))) short bf16x8;
typedef __attribute__((ext_vector_type(4))) short short4v;
typedef __attribute__((ext_vector_type(4))) float f32x4;
typedef __attribute__((ext_vector_type(2))) uint32_t u32x2;
typedef __attribute__((ext_vector_type(4))) uint32_t u32x4;

#define MFMA16(a, b, c) __builtin_amdgcn_mfma_f32_16x16x32_bf16((a), (b), (c), 0, 0, 0)

__device__ __forceinline__ short f2bf(float f) {
    uint32_t u = __builtin_bit_cast(uint32_t, f);
    u = (u + 0x7FFFu + ((u >> 16) & 1u)) >> 16;
    return (short)(uint16_t)u;
}

__device__ __forceinline__ uint32_t pkbf(float a, float b) {
#if __has_builtin(__builtin_amdgcn_cvt_pk_bf16_f32)
    auto r = __builtin_amdgcn_cvt_pk_bf16_f32(a, b);
    return __builtin_bit_cast(uint32_t, r);
#else
    return (uint32_t)(uint16_t)f2bf(a) | ((uint32_t)(uint16_t)f2bf(b) << 16);
#endif
}

__device__ __forceinline__ float fexp2(float x) {
#if __has_builtin(__builtin_amdgcn_exp2f)
    return __builtin_amdgcn_exp2f(x);
#else
    return exp2f(x);
#endif
}

// async global->LDS, 16B per lane; LDS dest = wave-uniform base + lane*16
__device__ __forceinline__ void gload16(const short* g, short* l) {
    __builtin_amdgcn_global_load_lds(
        (const __attribute__((address_space(1))) unsigned int*)g,
        (__attribute__((address_space(3))) unsigned int*)l, 16, 0, 0);
}

// ---------------- prep: all fp32->bf16 conversions + log2(mult) ----------------
// Flat exact-size grid (12292 blocks): [0,2048) weights, [2048,4096) Q,
// [4096,8192) K, [8192,12288) V, [12288,12292) multiplicities.
__global__ __launch_bounds__(256) void prep_kernel(
        const float* __restrict__ w0, const float* __restrict__ w1,
        const float* __restrict__ w2, const float* __restrict__ w3,
        const float* __restrict__ q, const float* __restrict__ k,
        const float* __restrict__ v, const float* __restrict__ m,
        short* __restrict__ wb, short* __restrict__ Qa,
        short* __restrict__ Ka, short* __restrict__ Va,
        float* __restrict__ lm) {
    const int bid = blockIdx.x;
    if (bid >= 12288) {
        const int i = ((bid - 12288) * 256 + threadIdx.x) * 8;
        f32x4 a = *(const f32x4*)(m + i);
        f32x4 b = *(const f32x4*)(m + i + 4);
        f32x4 oa, ob;
        #pragma unroll
        for (int j = 0; j < 4; ++j) { oa[j] = __log2f(a[j]); ob[j] = __log2f(b[j]); }
        *(f32x4*)(lm + i) = oa;
        *(f32x4*)(lm + i + 4) = ob;
        return;
    }
    const float* src;
    short* dst;
    int local;
    if (bid < 2048) {
        const int z = bid >> 9;
        local = bid & 511;
        src = (z == 0) ? w0 : (z == 1) ? w1 : (z == 2) ? w2 : w3;
        dst = wb + (size_t)z * 1048576;
    } else if (bid < 4096) { src = q; dst = Qa; local = bid - 2048; }
    else if (bid < 8192)   { src = k; dst = Ka; local = bid - 4096; }
    else                   { src = v; dst = Va; local = bid - 8192; }
    const size_t i = ((size_t)local * 256 + threadIdx.x) * 8;
    f32x4 a = *(const f32x4*)(src + i);
    f32x4 b = *(const f32x4*)(src + i + 4);
    u32x4 o = { pkbf(a[0], a[1]), pkbf(a[2], a[3]), pkbf(b[0], b[1]), pkbf(b[2], b[3]) };
    *(u32x4*)(dst + i) = o;
}

// ---------------- unified Q/K/V projection GEMM ----------------
// y: [0,32) Q -> Qp nshift=10; [32,96) K -> Kp nshift=11; [96,160) V -> Vt.
// Flat 1-D grid (nblk = ny*8, %8==0). XCD-chunked swizzle: hw XCD = bid&7;
// logical l = (bid&7)*cpx + bid>>3 gives each XCD a contiguous y-chunk across
// all 8 x (x fastest); per-XCD working set (~2MB A + 2MB W) fits the 4 MB L2.
// K-loop is 2-phase double-buffered (T3-minimum): STAGE(t+1) issued BEFORE
// compute(t), one barrier per K-step, so the glds latency hides under the
// 16-MFMA + 8-ds_read compute phase instead of stalling the block.
__global__ __launch_bounds__(256) void proj_kernel(
        const short* __restrict__ Qa, const short* __restrict__ Ka,
        const short* __restrict__ Va, const short* __restrict__ wb,
        const float* __restrict__ wq_b, const float* __restrict__ wk_b,
        const float* __restrict__ wv_b, short* __restrict__ Qp,
        short* __restrict__ Kp, short* __restrict__ Vt, const int ybase) {
    __shared__ short As[2][128 * 32];
    __shared__ short Bs[2][128 * 32];

    const int cpx = gridDim.x >> 3;
    const int l = (blockIdx.x & 7) * cpx + (blockIdx.x >> 3);
    const int y = (l >> 3) + ybase;
    const int tn = (l & 7) * 128;

    const short* A; const short* W; const float* bias; int mode, tm;
    if (y < 32)      { A = Qa; W = wb;           bias = wq_b; mode = 0; tm = y * 128; }
    else if (y < 96) { A = Ka; W = wb + 1048576; bias = wk_b; mode = 1; tm = (y - 32) * 128; }
    else             { A = Va; W = wb + 2097152; bias = wv_b; mode = 2; tm = (y - 96) * 128; }

    const int t = threadIdx.x, lane = t & 63, w = t >> 6;
    const int wr = w >> 1, wc = w & 1;
    const int qd = lane >> 4, c = lane & 15;

    f32x4 acc[4][4];
    #pragma unroll
    for (int i = 0; i < 4; ++i)
        #pragma unroll
        for (int j = 0; j < 4; ++j) acc[i][j] = (f32x4){0.f, 0.f, 0.f, 0.f};

    const int r0 = w * 16 + (lane >> 2);
    const int qc = (lane & 3) ^ ((lane >> 3) & 3);
    const short* ga0 = A + (size_t)(tm + r0) * 1024 + qc * 8;
    const short* ga1 = ga0 + 64 * 1024;
    const short* gb0 = W + (size_t)(tn + r0) * 1024 + qc * 8;
    const short* gb1 = gb0 + 64 * 1024;
    const int lofs = w * 512;
    const int swz = (qd ^ ((c >> 1) & 3)) * 8;

    auto stage = [&](int buf, int k0) {
        gload16(ga0 + k0, &As[buf][lofs]);
        gload16(ga1 + k0, &As[buf][lofs + 2048]);
        gload16(gb0 + k0, &Bs[buf][lofs]);
        gload16(gb1 + k0, &Bs[buf][lofs + 2048]);
    };
    auto compute = [&](const short* Ab, const short* Bb) {
        bf16x8 af[4], bfr[4];
        #pragma unroll
        for (int rt = 0; rt < 4; ++rt)
            af[rt] = *(const bf16x8*)&Ab[(wr * 64 + rt * 16 + c) * 32 + swz];
        #pragma unroll
        for (int ct = 0; ct < 4; ++ct)
            bfr[ct] = *(const bf16x8*)&Bb[(wc * 64 + ct * 16 + c) * 32 + swz];
        #pragma unroll
        for (int rt = 0; rt < 4; ++rt)
            #pragma unroll
            for (int ct = 0; ct < 4; ++ct)
                acc[rt][ct] = MFMA16(af[rt], bfr[ct], acc[rt][ct]);
    };

    stage(0, 0);
    __syncthreads();
    for (int k0 = 0; k0 < 1024; k0 += 64) {
        stage(1, k0 + 32);          // prefetch t+1 into buf1 (nobody reads buf1 yet)
        compute(As[0], Bs[0]);      // compute t from buf0
        __syncthreads();            // drains buf1 loads (latency hidden by compute)
        if (k0 + 64 < 1024)
            stage(0, k0 + 64);      // prefetch t+2 into buf0 (buf0 reads all done)
        compute(As[1], Bs[1]);      // compute t+1 from buf1
        __syncthreads();
    }

    float bv[4];
    #pragma unroll
    for (int ct = 0; ct < 4; ++ct) bv[ct] = bias[tn + wc * 64 + ct * 16 + c];

    if (mode == 2) {
        #pragma unroll
        for (int rt = 0; rt < 4; ++rt)
            #pragma unroll
            for (int ct = 0; ct < 4; ++ct) {
                const int cg = tn + wc * 64 + ct * 16 + c;
                const int h = cg >> 6, d = cg & 63;
                const int rg0 = tm + wr * 64 + rt * 16 + qd * 4;
                const int bb = rg0 >> 11, n = rg0 & 2047;
                u32x2 pk = { pkbf(acc[rt][ct][0] + bv[ct], acc[rt][ct][1] + bv[ct]),
                             pkbf(acc[rt][ct][2] + bv[ct], acc[rt][ct][3] + bv[ct]) };
                *(u32x2*)&Vt[((((size_t)(bb * 16 + h)) * 64 + d) << 11) + n] = pk;
            }
    } else {
        short* out = (mode == 0) ? Qp : Kp;
        const int nshift = (mode == 0) ? 10 : 11;
        const int mask = (1 << nshift) - 1;
        #pragma unroll
        for (int rt = 0; rt < 4; ++rt)
            #pragma unroll
            for (int ct = 0; ct < 4; ++ct) {
                const int cg = tn + wc * 64 + ct * 16 + c;
                const int h = cg >> 6, d = cg & 63;
                #pragma unroll
                for (int r = 0; r < 4; ++r) {
                    const int rg = tm + wr * 64 + rt * 16 + qd * 4 + r;
                    const int bb = rg >> nshift, n = rg & mask;
                    out[((((size_t)(bb * 16 + h)) << nshift) + n) * 64 + d] =
                        f2bf(acc[rt][ct][r] + bv[ct]);
                }
            }
    }
}

// ---------------- O projection GEMM: 128x64 tile, fp32 out ----------------
// Flat 512-block grid, XCD-chunked swizzle, same 2-phase double-buffered
// K-loop as proj_kernel.
__global__ __launch_bounds__(256, 4) void gemm_o_kernel(
        const short* __restrict__ Ob, const short* __restrict__ W,
        const float* __restrict__ bias, float* __restrict__ out) {
    __shared__ short As[2][128 * 32];
    __shared__ short Bs[2][64 * 32];

    const int cpx = gridDim.x >> 3;
    const int l = (blockIdx.x & 7) * cpx + (blockIdx.x >> 3);
    const int tm = (l >> 4) * 128, tn = (l & 15) * 64;

    const int t = threadIdx.x, lane = t & 63, w = t >> 6;
    const int wr = w >> 1, wc = w & 1;
    const int qd = lane >> 4, c = lane & 15;

    f32x4 acc[4][2];
    #pragma unroll
    for (int i = 0; i < 4; ++i)
        #pragma unroll
        for (int j = 0; j < 2; ++j) acc[i][j] = (f32x4){0.f, 0.f, 0.f, 0.f};

    const int r0 = w * 16 + (lane >> 2);
    const int qc = (lane & 3) ^ ((lane >> 3) & 3);
    const short* ga0 = Ob + (size_t)(tm + r0) * 1024 + qc * 8;
    const short* ga1 = ga0 + 64 * 1024;
    const short* gb0 = W + (size_t)(tn + r0) * 1024 + qc * 8;
    const int lofs = w * 512;
    const int swz = (qd ^ ((c >> 1) & 3)) * 8;

    auto stage = [&](int buf, int k0) {
        gload16(ga0 + k0, &As[buf][lofs]);
        gload16(ga1 + k0, &As[buf][lofs + 2048]);
        gload16(gb0 + k0, &Bs[buf][lofs]);
    };
    auto compute = [&](const short* Ab, const short* Bb) {
        bf16x8 af[4], bfr[2];
        #pragma unroll
        for (int rt = 0; rt < 4; ++rt)
            af[rt] = *(const bf16x8*)&Ab[(wr * 64 + rt * 16 + c) * 32 + swz];
        #pragma unroll
        for (int ct = 0; ct < 2; ++ct)
            bfr[ct] = *(const bf16x8*)&Bb[(wc * 32 + ct * 16 + c) * 32 + swz];
        #pragma unroll
        for (int rt = 0; rt < 4; ++rt)
            #pragma unroll
            for (int ct = 0; ct < 2; ++ct)
                acc[rt][ct] = MFMA16(af[rt], bfr[ct], acc[rt][ct]);
    };

    stage(0, 0);
    __syncthreads();
    for (int k0 = 0; k0 < 1024; k0 += 64) {
        stage(1, k0 + 32);
        compute(As[0], Bs[0]);
        __syncthreads();
        if (k0 + 64 < 1024)
            stage(0, k0 + 64);
        compute(As[1], Bs[1]);
        __syncthreads();
    }

    float bv[2];
    #pragma unroll
    for (int ct = 0; ct < 2; ++ct) bv[ct] = bias[tn + wc * 32 + ct * 16 + c];

    #pragma unroll
    for (int rt = 0; rt < 4; ++rt)
        #pragma unroll
        for (int ct = 0; ct < 2; ++ct) {
            const int cg = tn + wc * 32 + ct * 16 + c;
            #pragma unroll
            for (int r = 0; r < 4; ++r) {
                const int rg = tm + wr * 64 + rt * 16 + qd * 4 + r;
                out[(size_t)rg * 1024 + cg] = acc[rt][ct][r] + bv[ct];
            }
        }
}

// ---------------- flash attention: 128-q tile, fixed-base softmax ----------------
// Fixed-base softmax: p = exp2(s*SC + log2 m) with NO running max. Bound:
// |s| <= |q||k| <= 64 -> exp2 arg <= ~13.5 -> no overflow possible; bf16/fp32
// exponent range covers the full dynamic range, and the final division
// normalizes. Removes the per-iter max reduce + rescale (the R5 VALU wall).
// Row-sum l computed on the MFMA pipe via a constant ones-fragment (5th acc
// column tile) instead of VALU adds.
// Grid = 512 flat blocks; (bid&7) pins all 8 q-tiles of a (b,h) to one XCD.
__global__ __launch_bounds__(256, 2) void attn_kernel(
        const short* __restrict__ Qp, const short* __restrict__ Kp,
        const short* __restrict__ Vt, const float* __restrict__ logm,
        short* __restrict__ Ob) {
    __shared__ short Ps[128 * 128];   // 32 KB; Ks[128][64] aliases the front 16 KB
    __shared__ short Vs[64 * 128];    // 16 KB
    __shared__ float Lm[128];
    short* Ks = Ps;

    const int bid = blockIdx.x;
    const int xcd = bid & 7, ii = bid >> 3;
    const int qt = ii >> 3, bh = xcd + ((ii & 7) << 3);
    const int b = bh >> 4;
    const int t = threadIdx.x, lane = t & 63, w = t >> 6;
    const int qd = lane >> 4, c = lane & 15;
    const int cl = c & 7;
    const float SC = 0.18033688011112042f;   // 0.125 * log2(e)

    // Q frags (B-operand): lane holds Q[q = qt*128+w*32+ct*16+c][kd*32+qd*8 ..+7]
    bf16x8 qf[2][2];
    #pragma unroll
    for (int ct = 0; ct < 2; ++ct)
        #pragma unroll
        for (int kd = 0; kd < 2; ++kd)
            qf[ct][kd] = *(const bf16x8*)(Qp +
                ((size_t)bh * 1024 + qt * 128 + w * 32 + ct * 16 + c) * 64 + kd * 32 + qd * 8);

    // constant ones-fragment: B[n=64][k] = 1 for l = sum_k P (lanes c==0)
    bf16x8 onesf;
    {
        const short ov = (c == 0) ? (short)0x3F80 : (short)0;
        #pragma unroll
        for (int j = 0; j < 8; ++j) onesf[j] = ov;
    }

    f32x4 oacc[2][5];                 // [.][4] = l accumulator column
    #pragma unroll
    for (int i = 0; i < 2; ++i)
        #pragma unroll
        for (int j = 0; j < 5; ++j) oacc[i][j] = (f32x4){0.f, 0.f, 0.f, 0.f};

    // glds staging pointers (chunk-swizzled global source, linear LDS dest)
    const short* kgp[4];
    short* klp[4];
    const short* vgp[4];
    short* vlp[4];
    {
        const int krow = lane >> 3;
        const int kchk = (lane & 7) ^ krow;
        const int vrow = lane >> 4;
        #pragma unroll
        for (int i = 0; i < 4; ++i) {
            const int rk = w * 32 + i * 8 + krow;
            kgp[i] = Kp + ((size_t)bh * 2048 + rk) * 64 + kchk * 8;
            klp[i] = &Ks[(w * 4 + i) * 512];
            const int rv = w * 16 + i * 4 + vrow;
            const int vchk = (lane & 15) ^ (rv & 7);
            vgp[i] = Vt + ((size_t)bh * 64 + rv) * 2048 + vchk * 8;
            vlp[i] = &Vs[(w * 4 + i) * 512];
        }
    }

    for (int kt = 0; kt < 16; ++kt) {
        // ---- stage K (128x64) and V^T (64x128) via glds; Lm = log2 m ----
        #pragma unroll
        for (int i = 0; i < 4; ++i) {
            gload16(kgp[i] + (size_t)kt * 8192, klp[i]);
            gload16(vgp[i] + kt * 128, vlp[i]);
        }
        if (t < 128) Lm[t] = logm[b * 2048 + kt * 128 + t];
        __syncthreads();

        // ---- S^T = K . Q^T : D[key][q] ----
        f32x4 s[8][2];
        #pragma unroll
        for (int rt = 0; rt < 8; ++rt) {
            bf16x8 a0 = *(const bf16x8*)&Ks[(rt * 16 + c) * 64 + (qd ^ cl) * 8];
            bf16x8 a1 = *(const bf16x8*)&Ks[(rt * 16 + c) * 64 + ((4 | qd) ^ cl) * 8];
            #pragma unroll
            for (int ct = 0; ct < 2; ++ct) {
                f32x4 z = (f32x4){0.f, 0.f, 0.f, 0.f};
                s[rt][ct] = MFMA16(a1, qf[ct][1], MFMA16(a0, qf[ct][0], z));
            }
        }
        __syncthreads();   // all Ks reads done before Ps (aliased) is written

        // ---- fixed-base softmax: p = exp2(s*SC + lv), no max, no rescale ----
        #pragma unroll
        for (int rt = 0; rt < 8; ++rt) {
            f32x4 lv = *(const f32x4*)&Lm[rt * 16 + qd * 4];
            #pragma unroll
            for (int ct = 0; ct < 2; ++ct) {
                float p0 = fexp2(__builtin_fmaf(s[rt][ct][0], SC, lv[0]));
                float p1 = fexp2(__builtin_fmaf(s[rt][ct][1], SC, lv[1]));
                float p2 = fexp2(__builtin_fmaf(s[rt][ct][2], SC, lv[2]));
                float p3 = fexp2(__builtin_fmaf(s[rt][ct][3], SC, lv[3]));
                u32x2 pk = { pkbf(p0, p1), pkbf(p2, p3) };
                const int prow = w * 32 + ct * 16 + c;
                const int pch = (2 * rt + (qd >> 1)) ^ cl;
                *(u32x2*)&Ps[prow * 128 + pch * 8 + (qd & 1) * 4] = pk;
            }
        }

        // ---- P.V + l (wave-private P rows; ones-frag row sums on MFMA pipe) ----
        #pragma unroll
        for (int kk = 0; kk < 4; ++kk) {
            const int lch = ((kk * 4 + qd) ^ cl) * 8;
            bf16x8 pf[2], vf[4];
            #pragma unroll
            for (int rtq = 0; rtq < 2; ++rtq)
                pf[rtq] = *(const bf16x8*)&Ps[(w * 32 + rtq * 16 + c) * 128 + lch];
            #pragma unroll
            for (int ct = 0; ct < 4; ++ct)
                vf[ct] = *(const bf16x8*)&Vs[(ct * 16 + c) * 128 + lch];
            #pragma unroll
            for (int rtq = 0; rtq < 2; ++rtq) {
                #pragma unroll
                for (int ct = 0; ct < 4; ++ct)
                    oacc[rtq][ct] = MFMA16(pf[rtq], vf[ct], oacc[rtq][ct]);
                oacc[rtq][4] = MFMA16(pf[rtq], onesf, oacc[rtq][4]);
            }
        }
        __syncthreads();   // Ps/Vs reads complete before next staging
    }

    // ---- epilogue: O / l; l lives in oacc[.][4] at lanes c==0 ----
    const int h = bh & 15;
    float inv[2][4];
    #pragma unroll
    for (int rtq = 0; rtq < 2; ++rtq)
        #pragma unroll
        for (int r = 0; r < 4; ++r)
            inv[rtq][r] = 1.f / __shfl(oacc[rtq][4][r], qd * 16);
    #pragma unroll
    for (int rtq = 0; rtq < 2; ++rtq)
        #pragma unroll
        for (int ct = 0; ct < 4; ++ct)
            #pragma unroll
            for (int r = 0; r < 4; ++r) {
                const int qg = qt * 128 + w * 32 + rtq * 16 + qd * 4 + r;
                const int e = h * 64 + ct * 16 + c;
                Ob[((size_t)(b * 1024 + qg)) * 1024 + e] = f2bf(oacc[rtq][ct][r] * inv[rtq][r]);
            }
}

extern "C" void kernel_launch(void* const* d_in, const int* in_sizes, int n_in,
                              void* d_out, int out_size, void* d_ws, size_t ws_size,
                              hipStream_t stream) {
    (void)in_sizes; (void)n_in; (void)out_size;
    const float* query = (const float*)d_in[0];
    const float* key   = (const float*)d_in[1];
    const float* value = (const float*)d_in[2];
    const float* mult  = (const float*)d_in[3];
    const float* wq_w  = (const float*)d_in[4];
    const float* wq_b  = (const float*)d_in[5];
    const float* wk_w  = (const float*)d_in[6];
    const float* wk_b  = (const float*)d_in[7];
    const float* wv_w  = (const float*)d_in[8];
    const float* wv_b  = (const float*)d_in[9];
    const float* wo_w  = (const float*)d_in[10];
    const float* wo_b  = (const float*)d_in[11];
    float* out = (float*)d_out;

    char* ws = (char*)d_ws;
    const size_t MB = 1024 * 1024;
    const bool merged = ws_size >= 89 * MB;  // merged proj needs Vt disjoint from Qa/Ka

    short* wb = (short*)(ws + 0 * MB);
    short* Qa = (short*)(ws + 8 * MB);
    short* Ka = (short*)(ws + 16 * MB);
    short* Va = (short*)(ws + 32 * MB);
    short* Qp = (short*)(ws + 48 * MB);
    short* Kp = (short*)(ws + 56 * MB);
    short *Vt, *Ob; float* lm;
    if (merged) {
        Vt = (short*)(ws + 72 * MB);   // own region: written while Qa/Ka still live
        Ob = (short*)(ws + 8 * MB);    // Qa dead after proj
        lm = (float*)(ws + 88 * MB);
    } else {
        Vt = (short*)(ws + 8 * MB);    // Qa+Ka dead after first proj launch
        Ob = (short*)(ws + 32 * MB);   // Va dead after second proj launch
        lm = (float*)(ws + 72 * MB);
    }

    prep_kernel<<<dim3(12292), 256, 0, stream>>>(
        wq_w, wk_w, wv_w, wo_w, query, key, value, mult, wb, Qa, Ka, Va, lm);
    if (merged) {
        proj_kernel<<<dim3(1280), 256, 0, stream>>>(
            Qa, Ka, Va, wb, wq_b, wk_b, wv_b, Qp, Kp, Vt, 0);
    } else {
        proj_kernel<<<dim3(768), 256, 0, stream>>>(
            Qa, Ka, Va, wb, wq_b, wk_b, wv_b, Qp, Kp, Vt, 0);
        proj_kernel<<<dim3(512), 256, 0, stream>>>(
            Qa, Ka, Va, wb, wq_b, wk_b, wv_b, Qp, Kp, Vt, 96);
    }
    attn_kernel<<<dim3(512), 256, 0, stream>>>(Qp, Kp, Vt, lm, Ob);
    gemm_o_kernel<<<dim3(512), 256, 0, stream>>>(Ob, wb + 3145728, wo_b, out);
}

// Round 3
// 280.363 us; speedup vs baseline: 1.0635x; 1.0635x over previous
//
#include <hip/hip_runtime.h>
#include <hip/hip_bf16.h>
#include <stdint.h>
#include <stddef.h>

typedef __attribute__((ext_vector_type(8))) short bf16x8;
typedef __attribute__((ext_vector_type(4))) short short4v;
typedef __attribute__((ext_vector_type(4))) float f32x4;
typedef __attribute__((ext_vector_type(2))) uint32_t u32x2;
typedef __attribute__((ext_vector_type(4))) uint32_t u32x4;

#define MFMA16(a, b, c) __builtin_amdgcn_mfma_f32_16x16x32_bf16((a), (b), (c), 0, 0, 0)

__device__ __forceinline__ short f2bf(float f) {
    uint32_t u = __builtin_bit_cast(uint32_t, f);
    u = (u + 0x7FFFu + ((u >> 16) & 1u)) >> 16;
    return (short)(uint16_t)u;
}

__device__ __forceinline__ uint32_t pkbf(float a, float b) {
#if __has_builtin(__builtin_amdgcn_cvt_pk_bf16_f32)
    auto r = __builtin_amdgcn_cvt_pk_bf16_f32(a, b);
    return __builtin_bit_cast(uint32_t, r);
#else
    return (uint32_t)(uint16_t)f2bf(a) | ((uint32_t)(uint16_t)f2bf(b) << 16);
#endif
}

__device__ __forceinline__ float fexp2(float x) {
#if __has_builtin(__builtin_amdgcn_exp2f)
    return __builtin_amdgcn_exp2f(x);
#else
    return exp2f(x);
#endif
}

// async global->LDS, 16B per lane; LDS dest = wave-uniform base + lane*16
__device__ __forceinline__ void gload16(const short* g, short* l) {
    __builtin_amdgcn_global_load_lds(
        (const __attribute__((address_space(1))) unsigned int*)g,
        (__attribute__((address_space(3))) unsigned int*)l, 16, 0, 0);
}

// ---------------- prep: all fp32->bf16 conversions + log2(mult) ----------------
// Flat exact-size grid (12292 blocks): [0,2048) weights, [2048,4096) Q,
// [4096,8192) K, [8192,12288) V, [12288,12292) multiplicities.
__global__ __launch_bounds__(256) void prep_kernel(
        const float* __restrict__ w0, const float* __restrict__ w1,
        const float* __restrict__ w2, const float* __restrict__ w3,
        const float* __restrict__ q, const float* __restrict__ k,
        const float* __restrict__ v, const float* __restrict__ m,
        short* __restrict__ wb, short* __restrict__ Qa,
        short* __restrict__ Ka, short* __restrict__ Va,
        float* __restrict__ lm) {
    const int bid = blockIdx.x;
    if (bid >= 12288) {
        const int i = ((bid - 12288) * 256 + threadIdx.x) * 8;
        f32x4 a = *(const f32x4*)(m + i);
        f32x4 b = *(const f32x4*)(m + i + 4);
        f32x4 oa, ob;
        #pragma unroll
        for (int j = 0; j < 4; ++j) { oa[j] = __log2f(a[j]); ob[j] = __log2f(b[j]); }
        *(f32x4*)(lm + i) = oa;
        *(f32x4*)(lm + i + 4) = ob;
        return;
    }
    const float* src;
    short* dst;
    int local;
    if (bid < 2048) {
        const int z = bid >> 9;
        local = bid & 511;
        src = (z == 0) ? w0 : (z == 1) ? w1 : (z == 2) ? w2 : w3;
        dst = wb + (size_t)z * 1048576;
    } else if (bid < 4096) { src = q; dst = Qa; local = bid - 2048; }
    else if (bid < 8192)   { src = k; dst = Ka; local = bid - 4096; }
    else                   { src = v; dst = Va; local = bid - 8192; }
    const size_t i = ((size_t)local * 256 + threadIdx.x) * 8;
    f32x4 a = *(const f32x4*)(src + i);
    f32x4 b = *(const f32x4*)(src + i + 4);
    u32x4 o = { pkbf(a[0], a[1]), pkbf(a[2], a[3]), pkbf(b[0], b[1]), pkbf(b[2], b[3]) };
    *(u32x4*)(dst + i) = o;
}

// ---------------- unified Q/K/V projection GEMM ----------------
// y: [0,32) Q -> Qp nshift=10; [32,96) K -> Kp nshift=11; [96,160) V -> Vt.
// Flat 1-D grid (nblk = ny*8, %8==0). XCD-chunked swizzle: hw XCD = bid&7;
// logical l = (bid&7)*cpx + bid>>3 gives each XCD a contiguous y-chunk across
// all 8 x (x fastest); per-XCD working set (~2MB A + 2MB W) fits the 4 MB L2.
// BK=64: single-buffered, same 2-barrier sync structure as the verified BK=32
// version, but each drain covers 8 glds/wave + 32 MFMA + 16 ds_read — halves
// the barrier count and doubles compute per vmcnt(0) drain. (R1's explicit
// dbuf regressed per guide m99/m100; this is a payload change, not a sync
// change.) LDS 32 KB -> 5 blocks/CU LDS-limit, VGPR keeps it at 4.
__global__ __launch_bounds__(256) void proj_kernel(
        const short* __restrict__ Qa, const short* __restrict__ Ka,
        const short* __restrict__ Va, const short* __restrict__ wb,
        const float* __restrict__ wq_b, const float* __restrict__ wk_b,
        const float* __restrict__ wv_b, short* __restrict__ Qp,
        short* __restrict__ Kp, short* __restrict__ Vt, const int ybase) {
    __shared__ short As[2][128 * 32];   // [K-half][row-chunk layout]
    __shared__ short Bs[2][128 * 32];

    const int cpx = gridDim.x >> 3;
    const int l = (blockIdx.x & 7) * cpx + (blockIdx.x >> 3);
    const int y = (l >> 3) + ybase;
    const int tn = (l & 7) * 128;

    const short* A; const short* W; const float* bias; int mode, tm;
    if (y < 32)      { A = Qa; W = wb;           bias = wq_b; mode = 0; tm = y * 128; }
    else if (y < 96) { A = Ka; W = wb + 1048576; bias = wk_b; mode = 1; tm = (y - 32) * 128; }
    else             { A = Va; W = wb + 2097152; bias = wv_b; mode = 2; tm = (y - 96) * 128; }

    const int t = threadIdx.x, lane = t & 63, w = t >> 6;
    const int wr = w >> 1, wc = w & 1;
    const int qd = lane >> 4, c = lane & 15;

    f32x4 acc[4][4];
    #pragma unroll
    for (int i = 0; i < 4; ++i)
        #pragma unroll
        for (int j = 0; j < 4; ++j) acc[i][j] = (f32x4){0.f, 0.f, 0.f, 0.f};

    const int r0 = w * 16 + (lane >> 2);
    const int qc = (lane & 3) ^ ((lane >> 3) & 3);
    const short* ga0 = A + (size_t)(tm + r0) * 1024 + qc * 8;
    const short* ga1 = ga0 + 64 * 1024;
    const short* gb0 = W + (size_t)(tn + r0) * 1024 + qc * 8;
    const short* gb1 = gb0 + 64 * 1024;
    const int lofs = w * 512;
    const int swz = (qd ^ ((c >> 1) & 3)) * 8;

    for (int k0 = 0; k0 < 1024; k0 += 64) {
        __syncthreads();
        // stage both K-halves back-to-back: 8 outstanding glds per wave
        gload16(ga0 + k0,      &As[0][lofs]);
        gload16(ga1 + k0,      &As[0][lofs + 2048]);
        gload16(gb0 + k0,      &Bs[0][lofs]);
        gload16(gb1 + k0,      &Bs[0][lofs + 2048]);
        gload16(ga0 + k0 + 32, &As[1][lofs]);
        gload16(ga1 + k0 + 32, &As[1][lofs + 2048]);
        gload16(gb0 + k0 + 32, &Bs[1][lofs]);
        gload16(gb1 + k0 + 32, &Bs[1][lofs + 2048]);
        __syncthreads();
        #pragma unroll
        for (int kh = 0; kh < 2; ++kh) {
            bf16x8 af[4], bfr[4];
            #pragma unroll
            for (int rt = 0; rt < 4; ++rt)
                af[rt] = *(const bf16x8*)&As[kh][(wr * 64 + rt * 16 + c) * 32 + swz];
            #pragma unroll
            for (int ct = 0; ct < 4; ++ct)
                bfr[ct] = *(const bf16x8*)&Bs[kh][(wc * 64 + ct * 16 + c) * 32 + swz];
            #pragma unroll
            for (int rt = 0; rt < 4; ++rt)
                #pragma unroll
                for (int ct = 0; ct < 4; ++ct)
                    acc[rt][ct] = MFMA16(af[rt], bfr[ct], acc[rt][ct]);
        }
    }

    float bv[4];
    #pragma unroll
    for (int ct = 0; ct < 4; ++ct) bv[ct] = bias[tn + wc * 64 + ct * 16 + c];

    if (mode == 2) {
        #pragma unroll
        for (int rt = 0; rt < 4; ++rt)
            #pragma unroll
            for (int ct = 0; ct < 4; ++ct) {
                const int cg = tn + wc * 64 + ct * 16 + c;
                const int h = cg >> 6, d = cg & 63;
                const int rg0 = tm + wr * 64 + rt * 16 + qd * 4;
                const int bb = rg0 >> 11, n = rg0 & 2047;
                u32x2 pk = { pkbf(acc[rt][ct][0] + bv[ct], acc[rt][ct][1] + bv[ct]),
                             pkbf(acc[rt][ct][2] + bv[ct], acc[rt][ct][3] + bv[ct]) };
                *(u32x2*)&Vt[((((size_t)(bb * 16 + h)) * 64 + d) << 11) + n] = pk;
            }
    } else {
        short* out = (mode == 0) ? Qp : Kp;
        const int nshift = (mode == 0) ? 10 : 11;
        const int mask = (1 << nshift) - 1;
        #pragma unroll
        for (int rt = 0; rt < 4; ++rt)
            #pragma unroll
            for (int ct = 0; ct < 4; ++ct) {
                const int cg = tn + wc * 64 + ct * 16 + c;
                const int h = cg >> 6, d = cg & 63;
                #pragma unroll
                for (int r = 0; r < 4; ++r) {
                    const int rg = tm + wr * 64 + rt * 16 + qd * 4 + r;
                    const int bb = rg >> nshift, n = rg & mask;
                    out[((((size_t)(bb * 16 + h)) << nshift) + n) * 64 + d] =
                        f2bf(acc[rt][ct][r] + bv[ct]);
                }
            }
    }
}

// ---------------- O projection GEMM: 128x64 tile, fp32 out ----------------
// Flat 512-block grid, XCD-chunked swizzle, BK=64 single-buffered (same
// structure as proj_kernel).
__global__ __launch_bounds__(256, 4) void gemm_o_kernel(
        const short* __restrict__ Ob, const short* __restrict__ W,
        const float* __restrict__ bias, float* __restrict__ out) {
    __shared__ short As[2][128 * 32];
    __shared__ short Bs[2][64 * 32];

    const int cpx = gridDim.x >> 3;
    const int l = (blockIdx.x & 7) * cpx + (blockIdx.x >> 3);
    const int tm = (l >> 4) * 128, tn = (l & 15) * 64;

    const int t = threadIdx.x, lane = t & 63, w = t >> 6;
    const int wr = w >> 1, wc = w & 1;
    const int qd = lane >> 4, c = lane & 15;

    f32x4 acc[4][2];
    #pragma unroll
    for (int i = 0; i < 4; ++i)
        #pragma unroll
        for (int j = 0; j < 2; ++j) acc[i][j] = (f32x4){0.f, 0.f, 0.f, 0.f};

    const int r0 = w * 16 + (lane >> 2);
    const int qc = (lane & 3) ^ ((lane >> 3) & 3);
    const short* ga0 = Ob + (size_t)(tm + r0) * 1024 + qc * 8;
    const short* ga1 = ga0 + 64 * 1024;
    const short* gb0 = W + (size_t)(tn + r0) * 1024 + qc * 8;
    const int lofs = w * 512;
    const int swz = (qd ^ ((c >> 1) & 3)) * 8;

    for (int k0 = 0; k0 < 1024; k0 += 64) {
        __syncthreads();
        gload16(ga0 + k0,      &As[0][lofs]);
        gload16(ga1 + k0,      &As[0][lofs + 2048]);
        gload16(gb0 + k0,      &Bs[0][lofs]);
        gload16(ga0 + k0 + 32, &As[1][lofs]);
        gload16(ga1 + k0 + 32, &As[1][lofs + 2048]);
        gload16(gb0 + k0 + 32, &Bs[1][lofs]);
        __syncthreads();
        #pragma unroll
        for (int kh = 0; kh < 2; ++kh) {
            bf16x8 af[4], bfr[2];
            #pragma unroll
            for (int rt = 0; rt < 4; ++rt)
                af[rt] = *(const bf16x8*)&As[kh][(wr * 64 + rt * 16 + c) * 32 + swz];
            #pragma unroll
            for (int ct = 0; ct < 2; ++ct)
                bfr[ct] = *(const bf16x8*)&Bs[kh][(wc * 32 + ct * 16 + c) * 32 + swz];
            #pragma unroll
            for (int rt = 0; rt < 4; ++rt)
                #pragma unroll
                for (int ct = 0; ct < 2; ++ct)
                    acc[rt][ct] = MFMA16(af[rt], bfr[ct], acc[rt][ct]);
        }
    }

    float bv[2];
    #pragma unroll
    for (int ct = 0; ct < 2; ++ct) bv[ct] = bias[tn + wc * 32 + ct * 16 + c];

    #pragma unroll
    for (int rt = 0; rt < 4; ++rt)
        #pragma unroll
        for (int ct = 0; ct < 2; ++ct) {
            const int cg = tn + wc * 32 + ct * 16 + c;
            #pragma unroll
            for (int r = 0; r < 4; ++r) {
                const int rg = tm + wr * 64 + rt * 16 + qd * 4 + r;
                out[(size_t)rg * 1024 + cg] = acc[rt][ct][r] + bv[ct];
            }
        }
}

// ---------------- flash attention: 128-q tile, fixed-base softmax ----------------
// Fixed-base softmax: p = exp2(s*SC + log2 m) with NO running max. Bound:
// |s| <= |q||k| <= 64 -> exp2 arg <= ~13.5 -> no overflow possible; bf16/fp32
// exponent range covers the full dynamic range, and the final division
// normalizes. Removes the per-iter max reduce + rescale (the R5 VALU wall).
// Row-sum l computed on the MFMA pipe via a constant ones-fragment (5th acc
// column tile) instead of VALU adds.
// Grid = 512 flat blocks; (bid&7) pins all 8 q-tiles of a (b,h) to one XCD.
__global__ __launch_bounds__(256, 2) void attn_kernel(
        const short* __restrict__ Qp, const short* __restrict__ Kp,
        const short* __restrict__ Vt, const float* __restrict__ logm,
        short* __restrict__ Ob) {
    __shared__ short Ps[128 * 128];   // 32 KB; Ks[128][64] aliases the front 16 KB
    __shared__ short Vs[64 * 128];    // 16 KB
    __shared__ float Lm[128];
    short* Ks = Ps;

    const int bid = blockIdx.x;
    const int xcd = bid & 7, ii = bid >> 3;
    const int qt = ii >> 3, bh = xcd + ((ii & 7) << 3);
    const int b = bh >> 4;
    const int t = threadIdx.x, lane = t & 63, w = t >> 6;
    const int qd = lane >> 4, c = lane & 15;
    const int cl = c & 7;
    const float SC = 0.18033688011112042f;   // 0.125 * log2(e)

    // Q frags (B-operand): lane holds Q[q = qt*128+w*32+ct*16+c][kd*32+qd*8 ..+7]
    bf16x8 qf[2][2];
    #pragma unroll
    for (int ct = 0; ct < 2; ++ct)
        #pragma unroll
        for (int kd = 0; kd < 2; ++kd)
            qf[ct][kd] = *(const bf16x8*)(Qp +
                ((size_t)bh * 1024 + qt * 128 + w * 32 + ct * 16 + c) * 64 + kd * 32 + qd * 8);

    // constant ones-fragment: B[n=64][k] = 1 for l = sum_k P (lanes c==0)
    bf16x8 onesf;
    {
        const short ov = (c == 0) ? (short)0x3F80 : (short)0;
        #pragma unroll
        for (int j = 0; j < 8; ++j) onesf[j] = ov;
    }

    f32x4 oacc[2][5];                 // [.][4] = l accumulator column
    #pragma unroll
    for (int i = 0; i < 2; ++i)
        #pragma unroll
        for (int j = 0; j < 5; ++j) oacc[i][j] = (f32x4){0.f, 0.f, 0.f, 0.f};

    // glds staging pointers (chunk-swizzled global source, linear LDS dest)
    const short* kgp[4];
    short* klp[4];
    const short* vgp[4];
    short* vlp[4];
    {
        const int krow = lane >> 3;
        const int kchk = (lane & 7) ^ krow;
        const int vrow = lane >> 4;
        #pragma unroll
        for (int i = 0; i < 4; ++i) {
            const int rk = w * 32 + i * 8 + krow;
            kgp[i] = Kp + ((size_t)bh * 2048 + rk) * 64 + kchk * 8;
            klp[i] = &Ks[(w * 4 + i) * 512];
            const int rv = w * 16 + i * 4 + vrow;
            const int vchk = (lane & 15) ^ (rv & 7);
            vgp[i] = Vt + ((size_t)bh * 64 + rv) * 2048 + vchk * 8;
            vlp[i] = &Vs[(w * 4 + i) * 512];
        }
    }

    for (int kt = 0; kt < 16; ++kt) {
        // ---- stage K (128x64) and V^T (64x128) via glds; Lm = log2 m ----
        #pragma unroll
        for (int i = 0; i < 4; ++i) {
            gload16(kgp[i] + (size_t)kt * 8192, klp[i]);
            gload16(vgp[i] + kt * 128, vlp[i]);
        }
        if (t < 128) Lm[t] = logm[b * 2048 + kt * 128 + t];
        __syncthreads();

        // ---- S^T = K . Q^T : D[key][q] ----
        f32x4 s[8][2];
        #pragma unroll
        for (int rt = 0; rt < 8; ++rt) {
            bf16x8 a0 = *(const bf16x8*)&Ks[(rt * 16 + c) * 64 + (qd ^ cl) * 8];
            bf16x8 a1 = *(const bf16x8*)&Ks[(rt * 16 + c) * 64 + ((4 | qd) ^ cl) * 8];
            #pragma unroll
            for (int ct = 0; ct < 2; ++ct) {
                f32x4 z = (f32x4){0.f, 0.f, 0.f, 0.f};
                s[rt][ct] = MFMA16(a1, qf[ct][1], MFMA16(a0, qf[ct][0], z));
            }
        }
        __syncthreads();   // all Ks reads done before Ps (aliased) is written

        // ---- fixed-base softmax: p = exp2(s*SC + lv), no max, no rescale ----
        #pragma unroll
        for (int rt = 0; rt < 8; ++rt) {
            f32x4 lv = *(const f32x4*)&Lm[rt * 16 + qd * 4];
            #pragma unroll
            for (int ct = 0; ct < 2; ++ct) {
                float p0 = fexp2(__builtin_fmaf(s[rt][ct][0], SC, lv[0]));
                float p1 = fexp2(__builtin_fmaf(s[rt][ct][1], SC, lv[1]));
                float p2 = fexp2(__builtin_fmaf(s[rt][ct][2], SC, lv[2]));
                float p3 = fexp2(__builtin_fmaf(s[rt][ct][3], SC, lv[3]));
                u32x2 pk = { pkbf(p0, p1), pkbf(p2, p3) };
                const int prow = w * 32 + ct * 16 + c;
                const int pch = (2 * rt + (qd >> 1)) ^ cl;
                *(u32x2*)&Ps[prow * 128 + pch * 8 + (qd & 1) * 4] = pk;
            }
        }

        // ---- P.V + l (wave-private P rows; ones-frag row sums on MFMA pipe) ----
        #pragma unroll
        for (int kk = 0; kk < 4; ++kk) {
            const int lch = ((kk * 4 + qd) ^ cl) * 8;
            bf16x8 pf[2], vf[4];
            #pragma unroll
            for (int rtq = 0; rtq < 2; ++rtq)
                pf[rtq] = *(const bf16x8*)&Ps[(w * 32 + rtq * 16 + c) * 128 + lch];
            #pragma unroll
            for (int ct = 0; ct < 4; ++ct)
                vf[ct] = *(const bf16x8*)&Vs[(ct * 16 + c) * 128 + lch];
            #pragma unroll
            for (int rtq = 0; rtq < 2; ++rtq) {
                #pragma unroll
                for (int ct = 0; ct < 4; ++ct)
                    oacc[rtq][ct] = MFMA16(pf[rtq], vf[ct], oacc[rtq][ct]);
                oacc[rtq][4] = MFMA16(pf[rtq], onesf, oacc[rtq][4]);
            }
        }
        __syncthreads();   // Ps/Vs reads complete before next staging
    }

    // ---- epilogue: O / l; l lives in oacc[.][4] at lanes c==0 ----
    const int h = bh & 15;
    float inv[2][4];
    #pragma unroll
    for (int rtq = 0; rtq < 2; ++rtq)
        #pragma unroll
        for (int r = 0; r < 4; ++r)
            inv[rtq][r] = 1.f / __shfl(oacc[rtq][4][r], qd * 16);
    #pragma unroll
    for (int rtq = 0; rtq < 2; ++rtq)
        #pragma unroll
        for (int ct = 0; ct < 4; ++ct)
            #pragma unroll
            for (int r = 0; r < 4; ++r) {
                const int qg = qt * 128 + w * 32 + rtq * 16 + qd * 4 + r;
                const int e = h * 64 + ct * 16 + c;
                Ob[((size_t)(b * 1024 + qg)) * 1024 + e] = f2bf(oacc[rtq][ct][r] * inv[rtq][r]);
            }
}

extern "C" void kernel_launch(void* const* d_in, const int* in_sizes, int n_in,
                              void* d_out, int out_size, void* d_ws, size_t ws_size,
                              hipStream_t stream) {
    (void)in_sizes; (void)n_in; (void)out_size;
    const float* query = (const float*)d_in[0];
    const float* key   = (const float*)d_in[1];
    const float* value = (const float*)d_in[2];
    const float* mult  = (const float*)d_in[3];
    const float* wq_w  = (const float*)d_in[4];
    const float* wq_b  = (const float*)d_in[5];
    const float* wk_w  = (const float*)d_in[6];
    const float* wk_b  = (const float*)d_in[7];
    const float* wv_w  = (const float*)d_in[8];
    const float* wv_b  = (const float*)d_in[9];
    const float* wo_w  = (const float*)d_in[10];
    const float* wo_b  = (const float*)d_in[11];
    float* out = (float*)d_out;

    char* ws = (char*)d_ws;
    const size_t MB = 1024 * 1024;
    const bool merged = ws_size >= 89 * MB;  // merged proj needs Vt disjoint from Qa/Ka

    short* wb = (short*)(ws + 0 * MB);
    short* Qa = (short*)(ws + 8 * MB);
    short* Ka = (short*)(ws + 16 * MB);
    short* Va = (short*)(ws + 32 * MB);
    short* Qp = (short*)(ws + 48 * MB);
    short* Kp = (short*)(ws + 56 * MB);
    short *Vt, *Ob; float* lm;
    if (merged) {
        Vt = (short*)(ws + 72 * MB);   // own region: written while Qa/Ka still live
        Ob = (short*)(ws + 8 * MB);    // Qa dead after proj
        lm = (float*)(ws + 88 * MB);
    } else {
        Vt = (short*)(ws + 8 * MB);    // Qa+Ka dead after first proj launch
        Ob = (short*)(ws + 32 * MB);   // Va dead after second proj launch
        lm = (float*)(ws + 72 * MB);
    }

    prep_kernel<<<dim3(12292), 256, 0, stream>>>(
        wq_w, wk_w, wv_w, wo_w, query, key, value, mult, wb, Qa, Ka, Va, lm);
    if (merged) {
        proj_kernel<<<dim3(1280), 256, 0, stream>>>(
            Qa, Ka, Va, wb, wq_b, wk_b, wv_b, Qp, Kp, Vt, 0);
    } else {
        proj_kernel<<<dim3(768), 256, 0, stream>>>(
            Qa, Ka, Va, wb, wq_b, wk_b, wv_b, Qp, Kp, Vt, 0);
        proj_kernel<<<dim3(512), 256, 0, stream>>>(
            Qa, Ka, Va, wb, wq_b, wk_b, wv_b, Qp, Kp, Vt, 96);
    }
    attn_kernel<<<dim3(512), 256, 0, stream>>>(Qp, Kp, Vt, lm, Ob);
    gemm_o_kernel<<<dim3(512), 256, 0, stream>>>(Ob, wb + 3145728, wo_b, out);
}

// Round 4
// 273.356 us; speedup vs baseline: 1.0908x; 1.0256x over previous
//
#include <hip/hip_runtime.h>
#include <hip/hip_bf16.h>
#include <stdint.h>
#include <stddef.h>

typedef __attribute__((ext_vector_type(8))) short bf16x8;
typedef __attribute__((ext_vector_type(4))) short short4v;
typedef __attribute__((ext_vector_type(4))) float f32x4;
typedef __attribute__((ext_vector_type(2))) uint32_t u32x2;
typedef __attribute__((ext_vector_type(4))) uint32_t u32x4;

#define MFMA16(a, b, c) __builtin_amdgcn_mfma_f32_16x16x32_bf16((a), (b), (c), 0, 0, 0)

__device__ __forceinline__ short f2bf(float f) {
    uint32_t u = __builtin_bit_cast(uint32_t, f);
    u = (u + 0x7FFFu + ((u >> 16) & 1u)) >> 16;
    return (short)(uint16_t)u;
}

__device__ __forceinline__ uint32_t pkbf(float a, float b) {
#if __has_builtin(__builtin_amdgcn_cvt_pk_bf16_f32)
    auto r = __builtin_amdgcn_cvt_pk_bf16_f32(a, b);
    return __builtin_bit_cast(uint32_t, r);
#else
    return (uint32_t)(uint16_t)f2bf(a) | ((uint32_t)(uint16_t)f2bf(b) << 16);
#endif
}

__device__ __forceinline__ float fexp2(float x) {
#if __has_builtin(__builtin_amdgcn_exp2f)
    return __builtin_amdgcn_exp2f(x);
#else
    return exp2f(x);
#endif
}

// async global->LDS, 16B per lane; LDS dest = wave-uniform base + lane*16
__device__ __forceinline__ void gload16(const short* g, short* l) {
    __builtin_amdgcn_global_load_lds(
        (const __attribute__((address_space(1))) unsigned int*)g,
        (__attribute__((address_space(3))) unsigned int*)l, 16, 0, 0);
}

// ---------------- prep: all fp32->bf16 conversions + log2(mult) ----------------
// Flat exact-size grid (12292 blocks): [0,2048) weights, [2048,4096) Q,
// [4096,8192) K, [8192,12288) V, [12288,12292) multiplicities.
__global__ __launch_bounds__(256) void prep_kernel(
        const float* __restrict__ w0, const float* __restrict__ w1,
        const float* __restrict__ w2, const float* __restrict__ w3,
        const float* __restrict__ q, const float* __restrict__ k,
        const float* __restrict__ v, const float* __restrict__ m,
        short* __restrict__ wb, short* __restrict__ Qa,
        short* __restrict__ Ka, short* __restrict__ Va,
        float* __restrict__ lm) {
    const int bid = blockIdx.x;
    if (bid >= 12288) {
        const int i = ((bid - 12288) * 256 + threadIdx.x) * 8;
        f32x4 a = *(const f32x4*)(m + i);
        f32x4 b = *(const f32x4*)(m + i + 4);
        f32x4 oa, ob;
        #pragma unroll
        for (int j = 0; j < 4; ++j) { oa[j] = __log2f(a[j]); ob[j] = __log2f(b[j]); }
        *(f32x4*)(lm + i) = oa;
        *(f32x4*)(lm + i + 4) = ob;
        return;
    }
    const float* src;
    short* dst;
    int local;
    if (bid < 2048) {
        const int z = bid >> 9;
        local = bid & 511;
        src = (z == 0) ? w0 : (z == 1) ? w1 : (z == 2) ? w2 : w3;
        dst = wb + (size_t)z * 1048576;
    } else if (bid < 4096) { src = q; dst = Qa; local = bid - 2048; }
    else if (bid < 8192)   { src = k; dst = Ka; local = bid - 4096; }
    else                   { src = v; dst = Va; local = bid - 8192; }
    const size_t i = ((size_t)local * 256 + threadIdx.x) * 8;
    f32x4 a = *(const f32x4*)(src + i);
    f32x4 b = *(const f32x4*)(src + i + 4);
    u32x4 o = { pkbf(a[0], a[1]), pkbf(a[2], a[3]), pkbf(b[0], b[1]), pkbf(b[2], b[3]) };
    *(u32x4*)(dst + i) = o;
}

// ---------------- unified Q/K/V projection GEMM ----------------
// y: [0,32) Q -> Qp nshift=10; [32,96) K -> Kp nshift=11; [96,160) V -> Vt.
// Flat 1-D grid (nblk = ny*8, %8==0). XCD-chunked swizzle: hw XCD = bid&7;
// logical l = (bid&7)*cpx + bid>>3 gives each XCD a contiguous y-chunk across
// all 8 x (x fastest); per-XCD working set (~2MB A + 2MB W) fits the 4 MB L2.
// BK=128 single-buffered, verified 2-barrier sync structure: each drain now
// covers 16 glds/wave + 64 MFMA + 32 ds_read. Residency is register-capped at
// 2 blocks/CU (120 arch VGPR + 64 acc AGPR), so the 64 KB LDS is free
// (m132's BK=128 cliff was 3->2 blocks; we are already at 2).
__global__ __launch_bounds__(256) void proj_kernel(
        const short* __restrict__ Qa, const short* __restrict__ Ka,
        const short* __restrict__ Va, const short* __restrict__ wb,
        const float* __restrict__ wq_b, const float* __restrict__ wk_b,
        const float* __restrict__ wv_b, short* __restrict__ Qp,
        short* __restrict__ Kp, short* __restrict__ Vt, const int ybase) {
    __shared__ short As[4][128 * 32];   // [K-chunk][row-chunk layout] 32 KB
    __shared__ short Bs[4][128 * 32];   // 32 KB

    const int cpx = gridDim.x >> 3;
    const int l = (blockIdx.x & 7) * cpx + (blockIdx.x >> 3);
    const int y = (l >> 3) + ybase;
    const int tn = (l & 7) * 128;

    const short* A; const short* W; const float* bias; int mode, tm;
    if (y < 32)      { A = Qa; W = wb;           bias = wq_b; mode = 0; tm = y * 128; }
    else if (y < 96) { A = Ka; W = wb + 1048576; bias = wk_b; mode = 1; tm = (y - 32) * 128; }
    else             { A = Va; W = wb + 2097152; bias = wv_b; mode = 2; tm = (y - 96) * 128; }

    const int t = threadIdx.x, lane = t & 63, w = t >> 6;
    const int wr = w >> 1, wc = w & 1;
    const int qd = lane >> 4, c = lane & 15;

    f32x4 acc[4][4];
    #pragma unroll
    for (int i = 0; i < 4; ++i)
        #pragma unroll
        for (int j = 0; j < 4; ++j) acc[i][j] = (f32x4){0.f, 0.f, 0.f, 0.f};

    const int r0 = w * 16 + (lane >> 2);
    const int qc = (lane & 3) ^ ((lane >> 3) & 3);
    const short* ga0 = A + (size_t)(tm + r0) * 1024 + qc * 8;
    const short* ga1 = ga0 + 64 * 1024;
    const short* gb0 = W + (size_t)(tn + r0) * 1024 + qc * 8;
    const short* gb1 = gb0 + 64 * 1024;
    const int lofs = w * 512;
    const int swz = (qd ^ ((c >> 1) & 3)) * 8;

    for (int k0 = 0; k0 < 1024; k0 += 128) {
        __syncthreads();
        // stage all 4 K-chunks back-to-back: 16 outstanding glds per wave
        #pragma unroll
        for (int kh = 0; kh < 4; ++kh) {
            gload16(ga0 + k0 + kh * 32, &As[kh][lofs]);
            gload16(ga1 + k0 + kh * 32, &As[kh][lofs + 2048]);
            gload16(gb0 + k0 + kh * 32, &Bs[kh][lofs]);
            gload16(gb1 + k0 + kh * 32, &Bs[kh][lofs + 2048]);
        }
        __syncthreads();
        #pragma unroll
        for (int kh = 0; kh < 4; ++kh) {
            bf16x8 af[4], bfr[4];
            #pragma unroll
            for (int rt = 0; rt < 4; ++rt)
                af[rt] = *(const bf16x8*)&As[kh][(wr * 64 + rt * 16 + c) * 32 + swz];
            #pragma unroll
            for (int ct = 0; ct < 4; ++ct)
                bfr[ct] = *(const bf16x8*)&Bs[kh][(wc * 64 + ct * 16 + c) * 32 + swz];
            #pragma unroll
            for (int rt = 0; rt < 4; ++rt)
                #pragma unroll
                for (int ct = 0; ct < 4; ++ct)
                    acc[rt][ct] = MFMA16(af[rt], bfr[ct], acc[rt][ct]);
        }
    }

    float bv[4];
    #pragma unroll
    for (int ct = 0; ct < 4; ++ct) bv[ct] = bias[tn + wc * 64 + ct * 16 + c];

    if (mode == 2) {
        #pragma unroll
        for (int rt = 0; rt < 4; ++rt)
            #pragma unroll
            for (int ct = 0; ct < 4; ++ct) {
                const int cg = tn + wc * 64 + ct * 16 + c;
                const int h = cg >> 6, d = cg & 63;
                const int rg0 = tm + wr * 64 + rt * 16 + qd * 4;
                const int bb = rg0 >> 11, n = rg0 & 2047;
                u32x2 pk = { pkbf(acc[rt][ct][0] + bv[ct], acc[rt][ct][1] + bv[ct]),
                             pkbf(acc[rt][ct][2] + bv[ct], acc[rt][ct][3] + bv[ct]) };
                *(u32x2*)&Vt[((((size_t)(bb * 16 + h)) * 64 + d) << 11) + n] = pk;
            }
    } else {
        short* out = (mode == 0) ? Qp : Kp;
        const int nshift = (mode == 0) ? 10 : 11;
        const int mask = (1 << nshift) - 1;
        #pragma unroll
        for (int rt = 0; rt < 4; ++rt)
            #pragma unroll
            for (int ct = 0; ct < 4; ++ct) {
                const int cg = tn + wc * 64 + ct * 16 + c;
                const int h = cg >> 6, d = cg & 63;
                #pragma unroll
                for (int r = 0; r < 4; ++r) {
                    const int rg = tm + wr * 64 + rt * 16 + qd * 4 + r;
                    const int bb = rg >> nshift, n = rg & mask;
                    out[((((size_t)(bb * 16 + h)) << nshift) + n) * 64 + d] =
                        f2bf(acc[rt][ct][r] + bv[ct]);
                }
            }
    }
}

// ---------------- O projection GEMM: 128x64 tile, fp32 out ----------------
// Flat 512-block grid, XCD-chunked swizzle, BK=128 single-buffered (same
// structure as proj_kernel). LDS 48 KB -> 3 blocks/CU LDS-cap.
__global__ __launch_bounds__(256, 4) void gemm_o_kernel(
        const short* __restrict__ Ob, const short* __restrict__ W,
        const float* __restrict__ bias, float* __restrict__ out) {
    __shared__ short As[4][128 * 32];
    __shared__ short Bs[4][64 * 32];

    const int cpx = gridDim.x >> 3;
    const int l = (blockIdx.x & 7) * cpx + (blockIdx.x >> 3);
    const int tm = (l >> 4) * 128, tn = (l & 15) * 64;

    const int t = threadIdx.x, lane = t & 63, w = t >> 6;
    const int wr = w >> 1, wc = w & 1;
    const int qd = lane >> 4, c = lane & 15;

    f32x4 acc[4][2];
    #pragma unroll
    for (int i = 0; i < 4; ++i)
        #pragma unroll
        for (int j = 0; j < 2; ++j) acc[i][j] = (f32x4){0.f, 0.f, 0.f, 0.f};

    const int r0 = w * 16 + (lane >> 2);
    const int qc = (lane & 3) ^ ((lane >> 3) & 3);
    const short* ga0 = Ob + (size_t)(tm + r0) * 1024 + qc * 8;
    const short* ga1 = ga0 + 64 * 1024;
    const short* gb0 = W + (size_t)(tn + r0) * 1024 + qc * 8;
    const int lofs = w * 512;
    const int swz = (qd ^ ((c >> 1) & 3)) * 8;

    for (int k0 = 0; k0 < 1024; k0 += 128) {
        __syncthreads();
        #pragma unroll
        for (int kh = 0; kh < 4; ++kh) {
            gload16(ga0 + k0 + kh * 32, &As[kh][lofs]);
            gload16(ga1 + k0 + kh * 32, &As[kh][lofs + 2048]);
            gload16(gb0 + k0 + kh * 32, &Bs[kh][lofs]);
        }
        __syncthreads();
        #pragma unroll
        for (int kh = 0; kh < 4; ++kh) {
            bf16x8 af[4], bfr[2];
            #pragma unroll
            for (int rt = 0; rt < 4; ++rt)
                af[rt] = *(const bf16x8*)&As[kh][(wr * 64 + rt * 16 + c) * 32 + swz];
            #pragma unroll
            for (int ct = 0; ct < 2; ++ct)
                bfr[ct] = *(const bf16x8*)&Bs[kh][(wc * 32 + ct * 16 + c) * 32 + swz];
            #pragma unroll
            for (int rt = 0; rt < 4; ++rt)
                #pragma unroll
                for (int ct = 0; ct < 2; ++ct)
                    acc[rt][ct] = MFMA16(af[rt], bfr[ct], acc[rt][ct]);
        }
    }

    float bv[2];
    #pragma unroll
    for (int ct = 0; ct < 2; ++ct) bv[ct] = bias[tn + wc * 32 + ct * 16 + c];

    #pragma unroll
    for (int rt = 0; rt < 4; ++rt)
        #pragma unroll
        for (int ct = 0; ct < 2; ++ct) {
            const int cg = tn + wc * 32 + ct * 16 + c;
            #pragma unroll
            for (int r = 0; r < 4; ++r) {
                const int rg = tm + wr * 64 + rt * 16 + qd * 4 + r;
                out[(size_t)rg * 1024 + cg] = acc[rt][ct][r] + bv[ct];
            }
        }
}

// ---------------- flash attention: 128-q tile, fixed-base softmax ----------------
// Fixed-base softmax: p = exp2(s*SC + log2 m) with NO running max. Bound:
// |s| <= |q||k| <= 64 -> exp2 arg <= ~13.5 -> no overflow possible; bf16/fp32
// exponent range covers the full dynamic range, and the final division
// normalizes. Removes the per-iter max reduce + rescale (the R5 VALU wall).
// Row-sum l computed on the MFMA pipe via a constant ones-fragment (5th acc
// column tile) instead of VALU adds.
// Grid = 512 flat blocks; (bid&7) pins all 8 q-tiles of a (b,h) to one XCD.
__global__ __launch_bounds__(256, 2) void attn_kernel(
        const short* __restrict__ Qp, const short* __restrict__ Kp,
        const short* __restrict__ Vt, const float* __restrict__ logm,
        short* __restrict__ Ob) {
    __shared__ short Ps[128 * 128];   // 32 KB; Ks[128][64] aliases the front 16 KB
    __shared__ short Vs[64 * 128];    // 16 KB
    __shared__ float Lm[128];
    short* Ks = Ps;

    const int bid = blockIdx.x;
    const int xcd = bid & 7, ii = bid >> 3;
    const int qt = ii >> 3, bh = xcd + ((ii & 7) << 3);
    const int b = bh >> 4;
    const int t = threadIdx.x, lane = t & 63, w = t >> 6;
    const int qd = lane >> 4, c = lane & 15;
    const int cl = c & 7;
    const float SC = 0.18033688011112042f;   // 0.125 * log2(e)

    // Q frags (B-operand): lane holds Q[q = qt*128+w*32+ct*16+c][kd*32+qd*8 ..+7]
    bf16x8 qf[2][2];
    #pragma unroll
    for (int ct = 0; ct < 2; ++ct)
        #pragma unroll
        for (int kd = 0; kd < 2; ++kd)
            qf[ct][kd] = *(const bf16x8*)(Qp +
                ((size_t)bh * 1024 + qt * 128 + w * 32 + ct * 16 + c) * 64 + kd * 32 + qd * 8);

    // constant ones-fragment: B[n=64][k] = 1 for l = sum_k P (lanes c==0)
    bf16x8 onesf;
    {
        const short ov = (c == 0) ? (short)0x3F80 : (short)0;
        #pragma unroll
        for (int j = 0; j < 8; ++j) onesf[j] = ov;
    }

    f32x4 oacc[2][5];                 // [.][4] = l accumulator column
    #pragma unroll
    for (int i = 0; i < 2; ++i)
        #pragma unroll
        for (int j = 0; j < 5; ++j) oacc[i][j] = (f32x4){0.f, 0.f, 0.f, 0.f};

    // glds staging pointers (chunk-swizzled global source, linear LDS dest)
    const short* kgp[4];
    short* klp[4];
    const short* vgp[4];
    short* vlp[4];
    {
        const int krow = lane >> 3;
        const int kchk = (lane & 7) ^ krow;
        const int vrow = lane >> 4;
        #pragma unroll
        for (int i = 0; i < 4; ++i) {
            const int rk = w * 32 + i * 8 + krow;
            kgp[i] = Kp + ((size_t)bh * 2048 + rk) * 64 + kchk * 8;
            klp[i] = &Ks[(w * 4 + i) * 512];
            const int rv = w * 16 + i * 4 + vrow;
            const int vchk = (lane & 15) ^ (rv & 7);
            vgp[i] = Vt + ((size_t)bh * 64 + rv) * 2048 + vchk * 8;
            vlp[i] = &Vs[(w * 4 + i) * 512];
        }
    }

    for (int kt = 0; kt < 16; ++kt) {
        // ---- stage K (128x64) and V^T (64x128) via glds; Lm = log2 m ----
        #pragma unroll
        for (int i = 0; i < 4; ++i) {
            gload16(kgp[i] + (size_t)kt * 8192, klp[i]);
            gload16(vgp[i] + kt * 128, vlp[i]);
        }
        if (t < 128) Lm[t] = logm[b * 2048 + kt * 128 + t];
        __syncthreads();

        // ---- S^T = K . Q^T : D[key][q] ----
        f32x4 s[8][2];
        #pragma unroll
        for (int rt = 0; rt < 8; ++rt) {
            bf16x8 a0 = *(const bf16x8*)&Ks[(rt * 16 + c) * 64 + (qd ^ cl) * 8];
            bf16x8 a1 = *(const bf16x8*)&Ks[(rt * 16 + c) * 64 + ((4 | qd) ^ cl) * 8];
            #pragma unroll
            for (int ct = 0; ct < 2; ++ct) {
                f32x4 z = (f32x4){0.f, 0.f, 0.f, 0.f};
                s[rt][ct] = MFMA16(a1, qf[ct][1], MFMA16(a0, qf[ct][0], z));
            }
        }
        __syncthreads();   // all Ks reads done before Ps (aliased) is written

        // ---- fixed-base softmax: p = exp2(s*SC + lv), no max, no rescale ----
        #pragma unroll
        for (int rt = 0; rt < 8; ++rt) {
            f32x4 lv = *(const f32x4*)&Lm[rt * 16 + qd * 4];
            #pragma unroll
            for (int ct = 0; ct < 2; ++ct) {
                float p0 = fexp2(__builtin_fmaf(s[rt][ct][0], SC, lv[0]));
                float p1 = fexp2(__builtin_fmaf(s[rt][ct][1], SC, lv[1]));
                float p2 = fexp2(__builtin_fmaf(s[rt][ct][2], SC, lv[2]));
                float p3 = fexp2(__builtin_fmaf(s[rt][ct][3], SC, lv[3]));
                u32x2 pk = { pkbf(p0, p1), pkbf(p2, p3) };
                const int prow = w * 32 + ct * 16 + c;
                const int pch = (2 * rt + (qd >> 1)) ^ cl;
                *(u32x2*)&Ps[prow * 128 + pch * 8 + (qd & 1) * 4] = pk;
            }
        }

        // ---- P.V + l (wave-private P rows; ones-frag row sums on MFMA pipe) ----
        #pragma unroll
        for (int kk = 0; kk < 4; ++kk) {
            const int lch = ((kk * 4 + qd) ^ cl) * 8;
            bf16x8 pf[2], vf[4];
            #pragma unroll
            for (int rtq = 0; rtq < 2; ++rtq)
                pf[rtq] = *(const bf16x8*)&Ps[(w * 32 + rtq * 16 + c) * 128 + lch];
            #pragma unroll
            for (int ct = 0; ct < 4; ++ct)
                vf[ct] = *(const bf16x8*)&Vs[(ct * 16 + c) * 128 + lch];
            #pragma unroll
            for (int rtq = 0; rtq < 2; ++rtq) {
                #pragma unroll
                for (int ct = 0; ct < 4; ++ct)
                    oacc[rtq][ct] = MFMA16(pf[rtq], vf[ct], oacc[rtq][ct]);
                oacc[rtq][4] = MFMA16(pf[rtq], onesf, oacc[rtq][4]);
            }
        }
        __syncthreads();   // Ps/Vs reads complete before next staging
    }

    // ---- epilogue: O / l; l lives in oacc[.][4] at lanes c==0 ----
    const int h = bh & 15;
    float inv[2][4];
    #pragma unroll
    for (int rtq = 0; rtq < 2; ++rtq)
        #pragma unroll
        for (int r = 0; r < 4; ++r)
            inv[rtq][r] = 1.f / __shfl(oacc[rtq][4][r], qd * 16);
    #pragma unroll
    for (int rtq = 0; rtq < 2; ++rtq)
        #pragma unroll
        for (int ct = 0; ct < 4; ++ct)
            #pragma unroll
            for (int r = 0; r < 4; ++r) {
                const int qg = qt * 128 + w * 32 + rtq * 16 + qd * 4 + r;
                const int e = h * 64 + ct * 16 + c;
                Ob[((size_t)(b * 1024 + qg)) * 1024 + e] = f2bf(oacc[rtq][ct][r] * inv[rtq][r]);
            }
}

extern "C" void kernel_launch(void* const* d_in, const int* in_sizes, int n_in,
                              void* d_out, int out_size, void* d_ws, size_t ws_size,
                              hipStream_t stream) {
    (void)in_sizes; (void)n_in; (void)out_size;
    const float* query = (const float*)d_in[0];
    const float* key   = (const float*)d_in[1];
    const float* value = (const float*)d_in[2];
    const float* mult  = (const float*)d_in[3];
    const float* wq_w  = (const float*)d_in[4];
    const float* wq_b  = (const float*)d_in[5];
    const float* wk_w  = (const float*)d_in[6];
    const float* wk_b  = (const float*)d_in[7];
    const float* wv_w  = (const float*)d_in[8];
    const float* wv_b  = (const float*)d_in[9];
    const float* wo_w  = (const float*)d_in[10];
    const float* wo_b  = (const float*)d_in[11];
    float* out = (float*)d_out;

    char* ws = (char*)d_ws;
    const size_t MB = 1024 * 1024;
    const bool merged = ws_size >= 89 * MB;  // merged proj needs Vt disjoint from Qa/Ka

    short* wb = (short*)(ws + 0 * MB);
    short* Qa = (short*)(ws + 8 * MB);
    short* Ka = (short*)(ws + 16 * MB);
    short* Va = (short*)(ws + 32 * MB);
    short* Qp = (short*)(ws + 48 * MB);
    short* Kp = (short*)(ws + 56 * MB);
    short *Vt, *Ob; float* lm;
    if (merged) {
        Vt = (short*)(ws + 72 * MB);   // own region: written while Qa/Ka still live
        Ob = (short*)(ws + 8 * MB);    // Qa dead after proj
        lm = (float*)(ws + 88 * MB);
    } else {
        Vt = (short*)(ws + 8 * MB);    // Qa+Ka dead after first proj launch
        Ob = (short*)(ws + 32 * MB);   // Va dead after second proj launch
        lm = (float*)(ws + 72 * MB);
    }

    prep_kernel<<<dim3(12292), 256, 0, stream>>>(
        wq_w, wk_w, wv_w, wo_w, query, key, value, mult, wb, Qa, Ka, Va, lm);
    if (merged) {
        proj_kernel<<<dim3(1280), 256, 0, stream>>>(
            Qa, Ka, Va, wb, wq_b, wk_b, wv_b, Qp, Kp, Vt, 0);
    } else {
        proj_kernel<<<dim3(768), 256, 0, stream>>>(
            Qa, Ka, Va, wb, wq_b, wk_b, wv_b, Qp, Kp, Vt, 0);
        proj_kernel<<<dim3(512), 256, 0, stream>>>(
            Qa, Ka, Va, wb, wq_b, wk_b, wv_b, Qp, Kp, Vt, 96);
    }
    attn_kernel<<<dim3(512), 256, 0, stream>>>(Qp, Kp, Vt, lm, Ob);
    gemm_o_kernel<<<dim3(512), 256, 0, stream>>>(Ob, wb + 3145728, wo_b, out);
}